// Round 5
// baseline (69.077 us; speedup 1.0000x reference)
//
#include <hip/hip_runtime.h>

// ---------------------------------------------------------------------------
// out[b,o] = sum_{f,p} x0[b,f]*x[b,p]*W[o,f,p] + bias[o]
//   == GEMM C[4096,256] = A[4096,16384] * W^T,  A[b,f*128+p] = x0[b,f]*x[b,p]
// R5: R4's barrier-free K-loop, un-starved. R4's __launch_bounds__(512,2)
// capped VGPR at 128 -> the 64-reg x slice (xr) was demoted (VGPR=84,
// MfmaUtil 19%). Fix: bounds (512,1) -> 256-VGPR budget (grid is 1 block/CU
// anyway), plus an explicit even/odd software pipeline for the W stream
// (named double buffers bwA/bwB — no runtime-indexed register arrays, rule
// #20). W is prep-transposed so each B-frag load is one coalesced
// global_load_dwordx4 (1 KB/wave) served from L2. Zero LDS/barriers in-loop.
// 256 blocks (32 mb x 8 sk), 512 thr = 8 waves (2m x 4n), 32 K-steps BK=64.
// Split-K=8 via f32 atomics onto bias-initialized out.
// ---------------------------------------------------------------------------

typedef _Float16 f16x8 __attribute__((ext_vector_type(8)));
typedef float    f32x4 __attribute__((ext_vector_type(4)));

#define WS_WT_OFF 0
#define WS_XF_OFF 8388608
#define WS_NEEDED 9437184

__device__ __forceinline__ void gl_lds16(const void* g, void* l) {
  __builtin_amdgcn_global_load_lds(
      (const __attribute__((address_space(1))) void*)g,
      (__attribute__((address_space(3))) void*)l, 16, 0, 0);
}

// ------------------------------ prep kernel --------------------------------
// [0,524288): W f32->f16 into MFMA-fragment order:
//   WT byte addr = (kstep*16 + o/16)*2048 + ((k%64)/8)*256 + (o%16)*16 + (k%8)*2
//   -> a wave's B-frag (16 o x 32 k) = 1 KB contiguous.
// [524288,589824): x f32->f16 + XOR-seg swizzle (reader-matched).
// [589824,851968): out = bias (float4 groups).
__global__ __launch_bounds__(256) void prep_kernel(
    const float* __restrict__ x, const float* __restrict__ W,
    const float* __restrict__ bias, char* __restrict__ WT,
    _Float16* __restrict__ Xf, float* __restrict__ out)
{
  int i = blockIdx.x * 256 + threadIdx.x;
  if (i < 524288) {
    int o = i >> 11, k8 = i & 2047;        // k8: 8-elem k-granule within row o
    const float* s = W + ((size_t)o << 14) + ((size_t)k8 << 3);
    f16x8 h;
#pragma unroll
    for (int e = 0; e < 8; ++e) h[e] = (_Float16)s[e];
    int sg  = k8 >> 3;                     // global k-step 0..255
    int seg = k8 & 7;
    char* dst = WT + ((size_t)(sg * 16 + (o >> 4))) * 2048 + seg * 256 + (o & 15) * 16;
    *(f16x8*)dst = h;
  } else if (i < 589824) {
    int j = i - 524288;
    int r = j >> 4, seg = j & 15;
    const float* s = x + r * 128 + seg * 8;
    f16x8 h;
#pragma unroll
    for (int e = 0; e < 8; ++e) h[e] = (_Float16)s[e];
    int segp = seg ^ (r & 7);
    *(f16x8*)(Xf + r * 128 + segp * 8) = h;
  } else {
    int j = i - 589824;                    // float4 idx into out[4096][256]
    int c = (j * 4) & 255;
    ((float4*)out)[j] = *(const float4*)(bias + c);
  }
}

// ------------------------------ GEMM kernel --------------------------------
__global__ __launch_bounds__(512, 1) void gemm_kernel(
    const char* __restrict__ WT, const _Float16* __restrict__ Xf,
    const float* __restrict__ x0, float* __restrict__ out)
{
  __shared__ __align__(16) char x_s[32768];   // x tile [128 rows][128 p] f16 swz

  const int bid = blockIdx.x;
  const int mb  = bid >> 3;          // 0..31 : 128-row block
  const int sk  = bid & 7;           // 0..7  : split-K chunk (16 f-values)

  const int t   = threadIdx.x;
  const int l   = t & 63;
  const int wv  = t >> 6;
  const int wm  = wv >> 2;           // 0..1 : M half (64 rows each)
  const int wn  = wv & 3;            // 0..3 : N quarter (64 cols)
  const int lr  = l & 15;
  const int lg  = l >> 4;
  const int swz = lr & 7;

  // ---- prologue: stage x tile (32 KB) via gl_lds16, then into regs ----
  const char* XfB = (const char*)Xf + (size_t)mb * 32768;
#pragma unroll
  for (int i = 0; i < 4; ++i)
    gl_lds16(XfB + i * 8192 + t * 16, x_s + i * 8192 + t * 16);
  __syncthreads();

  // xr[m][ph][tt]: A-frag source, row = wm*64 + m*16 + lr,
  // k-window seg = (ph*8 + tt*4 + lg) ^ swz (prep-matched XOR swizzle).
  f16x8 xr[4][2][2];
  const int rowb = (wm * 64 + lr) * 256;
#pragma unroll
  for (int m = 0; m < 4; ++m)
#pragma unroll
    for (int h = 0; h < 2; ++h)
#pragma unroll
      for (int tt = 0; tt < 2; ++tt) {
        int seg = (h * 8 + tt * 4 + lg) ^ swz;
        xr[m][h][tt] = *(const f16x8*)(x_s + rowb + m * 4096 + seg * 16);
      }

  // per-lane x0 row pointer (f window of this split-K chunk)
  const float* x0p = x0 + (size_t)(mb * 128 + wm * 64 + lr) * 128 + sk * 16;
  // per-lane W stream pointer: o-group = wn*4, k-step base = sk*32
  const char* wt = WT + ((size_t)(sk * 32) * 16 + wn * 4) * 2048 + l * 16;

  f32x4 acc[4][4] = {};
  f16x8 bwA[4][2], bwB[4][2];
  _Float16 sh[4];

  // prime: step 0 fragments into bwA
#pragma unroll
  for (int nI = 0; nI < 4; ++nI)
#pragma unroll
    for (int tt = 0; tt < 2; ++tt)
      bwA[nI][tt] = *(const f16x8*)(wt + nI * 2048 + tt * 1024);

#define MFMA_STEP(BW, PH) \
  _Pragma("unroll") \
  for (int m = 0; m < 4; ++m) { \
    _Pragma("unroll") \
    for (int tt = 0; tt < 2; ++tt) { \
      f16x8 av = xr[m][PH][tt] * sh[m]; \
      _Pragma("unroll") \
      for (int nI = 0; nI < 4; ++nI) \
        acc[m][nI] = __builtin_amdgcn_mfma_f32_16x16x32_f16( \
            av, BW[nI][tt], acc[m][nI], 0, 0, 0); \
    } \
  }

  for (int s = 0; s < 32; s += 2) {
    // prefetch step s+1 (same f, ph=1) into bwB
    const char* wt1 = wt + 32768;
#pragma unroll
    for (int nI = 0; nI < 4; ++nI)
#pragma unroll
      for (int tt = 0; tt < 2; ++tt)
        bwB[nI][tt] = *(const f16x8*)(wt1 + nI * 2048 + tt * 1024);

#pragma unroll
    for (int m = 0; m < 4; ++m)
      sh[m] = (_Float16)x0p[(size_t)m * 2048 + (s >> 1)];

    MFMA_STEP(bwA, 0)

    // prefetch step s+2 into bwA (last iter reads past K-chunk end: lands in
    // the adjacent Xf region of ws — valid memory, values never consumed)
    const char* wt2 = wt + 65536;
#pragma unroll
    for (int nI = 0; nI < 4; ++nI)
#pragma unroll
      for (int tt = 0; tt < 2; ++tt)
        bwA[nI][tt] = *(const f16x8*)(wt2 + nI * 2048 + tt * 1024);

    MFMA_STEP(bwB, 1)

    wt += 65536;
  }
#undef MFMA_STEP

  // ---- epilogue: split-K accumulate (out pre-initialized to bias) ----
  // C/D layout: col = lane&15, row = (lane>>4)*4 + reg
  float* op = out + (size_t)(mb * 128 + wm * 64 + lg * 4) * 256 + wn * 64 + lr;
#pragma unroll
  for (int m = 0; m < 4; ++m)
#pragma unroll
    for (int nI = 0; nI < 4; ++nI)
#pragma unroll
      for (int r = 0; r < 4; ++r)
        unsafeAtomicAdd(op + (size_t)(m * 16 + r) * 256 + nI * 16,
                        acc[m][nI][r]);
}

// --------------------------- fallback (no ws) ------------------------------
__global__ __launch_bounds__(256) void naive_kernel(
    const float* __restrict__ x0, const float* __restrict__ x,
    const float* __restrict__ W, const float* __restrict__ bias,
    float* __restrict__ out)
{
  __shared__ float x0_s[16][128];
  __shared__ float x_s[16][128];
  const int tid = threadIdx.x;
  const int b0  = blockIdx.x * 16;
  for (int i = tid; i < 16 * 128; i += 256) {
    int bb = i >> 7, c = i & 127;
    x0_s[bb][c] = x0[(size_t)(b0 + bb) * 128 + c];
    x_s[bb][c]  = x[(size_t)(b0 + bb) * 128 + c];
  }
  __syncthreads();
  const int lane = tid & 63, wv = tid >> 6;
  for (int o = wv; o < 256; o += 4) {
    float acc[16];
#pragma unroll
    for (int bb = 0; bb < 16; ++bb) acc[bb] = 0.f;
    for (int it = 0; it < 256; ++it) {
      int k = it * 64 + lane;
      float wval = W[(size_t)o * 16384 + k];
      int f = k >> 7, p = k & 127;
#pragma unroll
      for (int bb = 0; bb < 16; ++bb)
        acc[bb] += wval * (x0_s[bb][f] * x_s[bb][p]);
    }
#pragma unroll
    for (int bb = 0; bb < 16; ++bb) {
      float v = acc[bb];
      for (int off = 32; off; off >>= 1) v += __shfl_down(v, off);
      if (lane == 0) out[(size_t)(b0 + bb) * 256 + o] = v + bias[o];
    }
  }
}

// ------------------------------- launcher ----------------------------------
extern "C" void kernel_launch(void* const* d_in, const int* in_sizes, int n_in,
                              void* d_out, int out_size, void* d_ws,
                              size_t ws_size, hipStream_t stream)
{
  const float* x0   = (const float*)d_in[0];
  const float* x    = (const float*)d_in[1];
  const float* W    = (const float*)d_in[2];
  const float* bias = (const float*)d_in[3];
  float* out = (float*)d_out;

  if (ws_size >= (size_t)WS_NEEDED) {
    char*     WT = (char*)d_ws + WS_WT_OFF;
    _Float16* Xf = (_Float16*)((char*)d_ws + WS_XF_OFF);
    prep_kernel<<<3328, 256, 0, stream>>>(x, W, bias, WT, Xf, out);
    gemm_kernel<<<256, 512, 0, stream>>>(WT, Xf, x0, out);
  } else {
    naive_kernel<<<256, 256, 0, stream>>>(x0, x, W, bias, out);
  }
}

// Round 6
// 64.382 us; speedup vs baseline: 1.0729x; 1.0729x over previous
//
#include <hip/hip_runtime.h>

// ---------------------------------------------------------------------------
// out[b,o] = sum_{f,p} x0[b,f]*x[b,p]*W[o,f,p] + bias[o]
//   == GEMM C[4096,256] = A[4096,16384] * W^T,  A[b,f*128+p] = x0[b,f]*x[b,p]
// R6: counted-vmcnt triple-buffer pipeline (T3-minimum + T4), R1 geometry.
// BM=128 x BN=256(full N), BK=64, splitK=8 -> 256 blocks (1/CU), 512 thr =
// 8 waves (2m x 4n, wave=64x64). x persistent in LDS (32KB, XOR-swizzled,
// gl_lds-staged); W streamed through w_s[3] 32KB slots: step k stages slot
// (k+2)%3 at step TOP, computes slot k%3, ends with s_waitcnt vmcnt(4)
// (NEVER 0 in main loop) + ONE s_barrier. Loop unrolled x6 -> all slot
// indices compile-time (no runtime LDS bases — R3's suspected pathology).
// No sched_barrier/setprio (m141: order-pinning regresses). x0 via
// transposed f32 LDS table (broadcast conflict-free reads; R1's 2.88M
// conflict fix). Split-K=8 via f32 atomics onto bias-initialized out.
// ---------------------------------------------------------------------------

typedef _Float16 f16x8 __attribute__((ext_vector_type(8)));
typedef float    f32x4 __attribute__((ext_vector_type(4)));

#define WS_WF_OFF 0
#define WS_XF_OFF 8388608
#define WS_NEEDED 9437184

__device__ __forceinline__ void gl_lds16(const void* g, void* l) {
  __builtin_amdgcn_global_load_lds(
      (const __attribute__((address_space(1))) void*)g,
      (__attribute__((address_space(3))) void*)l, 16, 0, 0);
}

#define BAR()    asm volatile("s_barrier" ::: "memory")
#define VMCNT4() asm volatile("s_waitcnt vmcnt(4)" ::: "memory")
#define VMCNT0() asm volatile("s_waitcnt vmcnt(0)" ::: "memory")

// ------------------------------ prep kernel --------------------------------
// [0,524288): W f32->f16, row-major [256][16384] with XOR seg-swizzle within
// each 64-elem k-window (key o&7). [524288,589824): x f32->f16, [4096][128]
// with XOR seg-swizzle (key r&7). [589824,851968): out = bias (float4).
__global__ __launch_bounds__(256) void prep_kernel(
    const float* __restrict__ x, const float* __restrict__ W,
    const float* __restrict__ bias, _Float16* __restrict__ Wf,
    _Float16* __restrict__ Xf, float* __restrict__ out)
{
  int i = blockIdx.x * 256 + threadIdx.x;
  if (i < 524288) {
    int o = i >> 11, k8 = i & 2047;
    int kk = k8 >> 3, seg = k8 & 7;
    const float* s = W + ((size_t)o << 14) + ((size_t)k8 << 3);
    f16x8 h;
#pragma unroll
    for (int e = 0; e < 8; ++e) h[e] = (_Float16)s[e];
    int segp = seg ^ (o & 7);
    *(f16x8*)(Wf + ((size_t)o << 14) + kk * 64 + segp * 8) = h;
  } else if (i < 589824) {
    int j = i - 524288;
    int r = j >> 4, seg = j & 15;
    const float* s = x + r * 128 + seg * 8;
    f16x8 h;
#pragma unroll
    for (int e = 0; e < 8; ++e) h[e] = (_Float16)s[e];
    int segp = seg ^ (r & 7);
    *(f16x8*)(Xf + r * 128 + segp * 8) = h;
  } else {
    int j = i - 589824;                 // float4 idx into out[4096][256]
    int c = (j * 4) & 255;
    ((float4*)out)[j] = *(const float4*)(bias + c);
  }
}

// ------------------------------ GEMM kernel --------------------------------
__global__ __launch_bounds__(512) void gemm_kernel(
    const _Float16* __restrict__ Wf, const _Float16* __restrict__ Xf,
    const float* __restrict__ x0, float* __restrict__ out)
{
  __shared__ __align__(16) char  x_s[32768];      // x [128 rows][128] f16 swz
  __shared__ __align__(16) char  w_s[3][32768];   // W [256 o][64 k] f16 swz x3
  __shared__ float x0t[2048];                     // x0^T [16 f][128 rows] f32

  const int bid = blockIdx.x;
  const int mb  = bid >> 3;          // 0..31 : 128-row block
  const int sk  = bid & 7;           // 0..7  : split-K chunk (16 f) -> XCD

  const int t   = threadIdx.x;
  const int l   = t & 63;
  const int wv  = t >> 6;
  const int wm  = wv >> 2;           // 0..1 : M half (64 rows)
  const int wn  = wv & 3;            // 0..3 : N quarter (64 o)
  const int lr  = l & 15;
  const int lg  = l >> 4;
  const int swz = lr & 7;

  // ---- prologue ----
  // x0 slice [128 rows][16 f] as float4 per thread (issued first so its
  // vmcnt wait doesn't drain the staging queue)
  const int prow = t >> 2, pf = t & 3;
  const float4 x0v =
      *(const float4*)(x0 + (size_t)(mb * 128 + prow) * 128 + sk * 16 + pf * 4);

  const char* XfB = (const char*)Xf + (size_t)mb * 32768;
#pragma unroll
  for (int i = 0; i < 4; ++i)
    gl_lds16(XfB + i * 8192 + t * 16, x_s + i * 8192 + t * 16);

  const char* WfB  = (const char*)Wf;   // row stride 32768 B
  const int kbase  = sk * 4096;         // byte offset of this chunk's k-window
#pragma unroll
  for (int i = 0; i < 4; ++i) {         // stage step 0 -> slot 0
    int d = i * 8192 + t * 16;
    gl_lds16(WfB + (size_t)(d >> 7) * 32768 + kbase + 0 * 128 + (d & 127),
             w_s[0] + d);
  }
#pragma unroll
  for (int i = 0; i < 4; ++i) {         // stage step 1 -> slot 1
    int d = i * 8192 + t * 16;
    gl_lds16(WfB + (size_t)(d >> 7) * 32768 + kbase + 1 * 128 + (d & 127),
             w_s[1] + d);
  }
  x0t[(pf * 4 + 0) * 128 + prow] = x0v.x;
  x0t[(pf * 4 + 1) * 128 + prow] = x0v.y;
  x0t[(pf * 4 + 2) * 128 + prow] = x0v.z;
  x0t[(pf * 4 + 3) * 128 + prow] = x0v.w;
  __syncthreads();                      // one-time full drain

  f32x4 acc[4][4] = {};
  const int xrb   = (wm * 64 + lr) * 256;   // byte base of lane's x row
  const int brow  = (wn * 64 + lr) * 128;   // byte base of lane's W row
  const int x0ri  = wm * 64 + lr;

  // STEP(K, RD, ST, PAR, DO_STAGE, VM): compute slot RD (=K%3), stage slot
  // ST (=(K+2)%3) at top, end with VM + barrier. RD/ST/PAR are literals.
#define STEP(K, RD, ST, PAR, DO_STAGE, VM) { \
    if (DO_STAGE) { \
      _Pragma("unroll") \
      for (int i = 0; i < 4; ++i) { \
        int d = i * 8192 + t * 16; \
        gl_lds16(WfB + (size_t)(d >> 7) * 32768 + kbase + ((K) + 2) * 128 + (d & 127), \
                 w_s[ST] + d); \
      } \
    } \
    const int fl_ = (K) >> 1; \
    _Float16 sh_[4]; \
    _Pragma("unroll") \
    for (int m = 0; m < 4; ++m) \
      sh_[m] = (_Float16)x0t[fl_ * 128 + x0ri + m * 16]; \
    _Pragma("unroll") \
    for (int tp = 0; tp < 2; ++tp) { \
      f16x8 bw_[4]; \
      _Pragma("unroll") \
      for (int n = 0; n < 4; ++n) \
        bw_[n] = *(const f16x8*)(w_s[RD] + brow + n * 2048 + \
                                 (((tp * 4 + lg) ^ swz) << 4)); \
      _Pragma("unroll") \
      for (int m = 0; m < 4; ++m) { \
        f16x8 av_ = *(const f16x8*)(x_s + xrb + m * 4096 + \
                     ((((PAR) * 8 + tp * 4 + lg) ^ swz) << 4)) * sh_[m]; \
        _Pragma("unroll") \
        for (int n = 0; n < 4; ++n) \
          acc[m][n] = __builtin_amdgcn_mfma_f32_16x16x32_f16( \
              av_, bw_[n], acc[m][n], 0, 0, 0); \
      } \
    } \
    VM; BAR(); \
  }

  for (int k3 = 0; k3 < 30; k3 += 6) {
    STEP(k3 + 0, 0, 2, 0, true, VMCNT4());
    STEP(k3 + 1, 1, 0, 1, true, VMCNT4());
    STEP(k3 + 2, 2, 1, 0, true, VMCNT4());
    STEP(k3 + 3, 0, 2, 1, true, VMCNT4());
    STEP(k3 + 4, 1, 0, 0, true, VMCNT4());
    STEP(k3 + 5, 2, 1, 1, true, VMCNT4());
  }
  STEP(30, 0, 0, 0, false, VMCNT0());
  STEP(31, 1, 0, 1, false, ;);
#undef STEP

  // ---- epilogue: split-K accumulate (out pre-initialized to bias) ----
  // C/D layout: col = lane&15, row = (lane>>4)*4 + reg
  float* op = out + (size_t)(mb * 128 + wm * 64 + lg * 4) * 256 + wn * 64 + lr;
#pragma unroll
  for (int m = 0; m < 4; ++m)
#pragma unroll
    for (int n = 0; n < 4; ++n)
#pragma unroll
      for (int r = 0; r < 4; ++r)
        unsafeAtomicAdd(op + (size_t)(m * 16 + r) * 256 + n * 16,
                        acc[m][n][r]);
}

// --------------------------- fallback (no ws) ------------------------------
__global__ __launch_bounds__(256) void naive_kernel(
    const float* __restrict__ x0, const float* __restrict__ x,
    const float* __restrict__ W, const float* __restrict__ bias,
    float* __restrict__ out)
{
  __shared__ float x0_s[16][128];
  __shared__ float x_s[16][128];
  const int tid = threadIdx.x;
  const int b0  = blockIdx.x * 16;
  for (int i = tid; i < 16 * 128; i += 256) {
    int bb = i >> 7, c = i & 127;
    x0_s[bb][c] = x0[(size_t)(b0 + bb) * 128 + c];
    x_s[bb][c]  = x[(size_t)(b0 + bb) * 128 + c];
  }
  __syncthreads();
  const int lane = tid & 63, wv = tid >> 6;
  for (int o = wv; o < 256; o += 4) {
    float acc[16];
#pragma unroll
    for (int bb = 0; bb < 16; ++bb) acc[bb] = 0.f;
    for (int it = 0; it < 256; ++it) {
      int k = it * 64 + lane;
      float wval = W[(size_t)o * 16384 + k];
      int f = k >> 7, p = k & 127;
#pragma unroll
      for (int bb = 0; bb < 16; ++bb)
        acc[bb] += wval * (x0_s[bb][f] * x_s[bb][p]);
    }
#pragma unroll
    for (int bb = 0; bb < 16; ++bb) {
      float v = acc[bb];
      for (int off = 32; off; off >>= 1) v += __shfl_down(v, off);
      if (lane == 0) out[(size_t)(b0 + bb) * 256 + o] = v + bias[o];
    }
  }
}

// ------------------------------- launcher ----------------------------------
extern "C" void kernel_launch(void* const* d_in, const int* in_sizes, int n_in,
                              void* d_out, int out_size, void* d_ws,
                              size_t ws_size, hipStream_t stream)
{
  const float* x0   = (const float*)d_in[0];
  const float* x    = (const float*)d_in[1];
  const float* W    = (const float*)d_in[2];
  const float* bias = (const float*)d_in[3];
  float* out = (float*)d_out;

  if (ws_size >= (size_t)WS_NEEDED) {
    _Float16* Wf = (_Float16*)((char*)d_ws + WS_WF_OFF);
    _Float16* Xf = (_Float16*)((char*)d_ws + WS_XF_OFF);
    prep_kernel<<<3328, 256, 0, stream>>>(x, W, bias, Wf, Xf, out);
    gemm_kernel<<<256, 512, 0, stream>>>(Wf, Xf, x0, out);
  } else {
    naive_kernel<<<256, 256, 0, stream>>>(x0, x, W, bias, out);
  }
}

// Round 7
// 57.440 us; speedup vs baseline: 1.2026x; 1.1209x over previous
//
#include <hip/hip_runtime.h>

// ---------------------------------------------------------------------------
// out[b,o] = sum_{f,p} x0[b,f]*x[b,p]*W[o,f,p] + bias[o]
//   == GEMM C[4096,256] = A[4096,16384] * W^T,  A[b,f*128+p] = x0[b,f]*x[b,p]
// R7: LDS-pipe relief. R1/R3/R6 all bound at ~600 TF by LDS read throughput
// (16 ds_read_b128/wave/step = 2 MFMA/read). A is rank-1 -> hold each wave's
// x slice in REGISTERS (xr, 64 VGPR, loaded once) and read only B from LDS
// (8 reads/wave/step = 4 MFMA/read). R4/R5's version of this failed because
// 512-thr blocks cap VGPR at 128 (2 waves/SIMD structural) -> xr demoted.
// Here: 256-thr blocks (4 waves 2m x 2n), 512 blocks (2/CU),
// __launch_bounds__(256,2) -> 256-VGPR cap, xr+acc+bw ~200 fits.
// K-loop = R6's proven skeleton: W triple-buffered 16KB slots, stage slot
// (K+2)%3 at step top, s_waitcnt vmcnt(4) (never 0) + ONE s_barrier per
// step, literal slot indices, no sched_barrier/setprio. sk=bid&7 keeps each
// W-chunk XCD-L2-resident. Split-K=8 via f32 atomics onto bias-init'd out.
// ---------------------------------------------------------------------------

typedef _Float16 f16x8 __attribute__((ext_vector_type(8)));
typedef float    f32x4 __attribute__((ext_vector_type(4)));

#define WS_WF_OFF 0
#define WS_XF_OFF 8388608
#define WS_NEEDED 9437184

__device__ __forceinline__ void gl_lds16(const void* g, void* l) {
  __builtin_amdgcn_global_load_lds(
      (const __attribute__((address_space(1))) void*)g,
      (__attribute__((address_space(3))) void*)l, 16, 0, 0);
}

#define BAR()    asm volatile("s_barrier" ::: "memory")
#define VMCNT4() asm volatile("s_waitcnt vmcnt(4)" ::: "memory")
#define VMCNT0() asm volatile("s_waitcnt vmcnt(0)" ::: "memory")

// ------------------------------ prep kernel --------------------------------
// [0,524288): W f32->f16, row-major [256][16384] + XOR seg-swizzle within
// each 64-elem k-window (key o&7). [524288,589824): x f32->f16, [4096][128]
// + XOR seg-swizzle (key r&7). [589824,851968): out = bias (float4 groups).
__global__ __launch_bounds__(256) void prep_kernel(
    const float* __restrict__ x, const float* __restrict__ W,
    const float* __restrict__ bias, _Float16* __restrict__ Wf,
    _Float16* __restrict__ Xf, float* __restrict__ out)
{
  int i = blockIdx.x * 256 + threadIdx.x;
  if (i < 524288) {
    int o = i >> 11, k8 = i & 2047;
    int kk = k8 >> 3, seg = k8 & 7;
    const float* s = W + ((size_t)o << 14) + ((size_t)k8 << 3);
    f16x8 h;
#pragma unroll
    for (int e = 0; e < 8; ++e) h[e] = (_Float16)s[e];
    int segp = seg ^ (o & 7);
    *(f16x8*)(Wf + ((size_t)o << 14) + kk * 64 + segp * 8) = h;
  } else if (i < 589824) {
    int j = i - 524288;
    int r = j >> 4, seg = j & 15;
    const float* s = x + r * 128 + seg * 8;
    f16x8 h;
#pragma unroll
    for (int e = 0; e < 8; ++e) h[e] = (_Float16)s[e];
    int segp = seg ^ (r & 7);
    *(f16x8*)(Xf + r * 128 + segp * 8) = h;
  } else {
    int j = i - 589824;                 // float4 idx into out[4096][256]
    int c = (j * 4) & 255;
    ((float4*)out)[j] = *(const float4*)(bias + c);
  }
}

// ------------------------------ GEMM kernel --------------------------------
__global__ __launch_bounds__(256, 2) void gemm_kernel(
    const _Float16* __restrict__ Wf, const _Float16* __restrict__ Xf,
    const float* __restrict__ x0, float* __restrict__ out)
{
  // [0,49152): W slots 0..2 (16 KB each); prologue aliases [0,32768) for x.
  // [49152,57344): x0t [16 f][128 rows] f32.
  __shared__ __align__(16) char smem[57344];
  float* x0t = (float*)(smem + 49152);

  const int bid = blockIdx.x;
  const int mb  = bid >> 4;          // 0..31 : 128-row block
  const int nb  = (bid >> 3) & 1;    // 0..1  : 128-o half
  const int sk  = bid & 7;           // 0..7  : split-K chunk -> XCD-resident

  const int t   = threadIdx.x;
  const int l   = t & 63;
  const int wv  = t >> 6;
  const int wm  = wv >> 1;           // 0..1 : 64-row half
  const int wn  = wv & 1;            // 0..1 : 64-o half
  const int lr  = l & 15;
  const int lg  = l >> 4;
  const int swz = lr & 7;

  // ---- Phase A: stage x tile (32 KB) into smem[0,32768); x0 -> regs ----
  const char* XfB = (const char*)Xf + (size_t)mb * 32768;
#pragma unroll
  for (int i = 0; i < 8; ++i)
    gl_lds16(XfB + i * 4096 + t * 16, smem + i * 4096 + t * 16);

  const int r0 = t >> 1, hf = t & 1;
  const float* x0s = x0 + (size_t)(mb * 128 + r0) * 128 + sk * 16 + hf * 8;
  const float4 xa = *(const float4*)(x0s);
  const float4 xb = *(const float4*)(x0s + 4);
  __syncthreads();                       // drains gl_lds + x0 loads

  // x0t transposed write (conflict-free broadcast reads in-loop)
  x0t[(hf * 8 + 0) * 128 + r0] = xa.x;
  x0t[(hf * 8 + 1) * 128 + r0] = xa.y;
  x0t[(hf * 8 + 2) * 128 + r0] = xa.z;
  x0t[(hf * 8 + 3) * 128 + r0] = xa.w;
  x0t[(hf * 8 + 4) * 128 + r0] = xb.x;
  x0t[(hf * 8 + 5) * 128 + r0] = xb.y;
  x0t[(hf * 8 + 6) * 128 + r0] = xb.z;
  x0t[(hf * 8 + 7) * 128 + r0] = xb.w;

  // ---- Phase B: x slice -> registers (once; static indices, rule #20) ----
  f16x8 xr[4][2][2];
  const int xrb = (wm * 64 + lr) * 256;
#pragma unroll
  for (int m = 0; m < 4; ++m)
#pragma unroll
    for (int h = 0; h < 2; ++h)
#pragma unroll
      for (int tt = 0; tt < 2; ++tt)
        xr[m][h][tt] = *(const f16x8*)(smem + xrb + m * 4096 +
                                       (((h * 8 + tt * 4 + lg) ^ swz) << 4));
  __syncthreads();                       // all waves done with x region

  // ---- Phase C: stage W slots 0,1 (x region now reusable) ----
  const char* WfB  = (const char*)Wf;
  const int  kbase = sk * 4096;          // byte offset of chunk's k-window
#pragma unroll
  for (int i = 0; i < 4; ++i) {
    int d = i * 4096 + t * 16;
    gl_lds16(WfB + (size_t)(nb * 128 + (d >> 7)) * 32768 + kbase + 0 * 128 + (d & 127),
             smem + 0 * 16384 + d);
  }
#pragma unroll
  for (int i = 0; i < 4; ++i) {
    int d = i * 4096 + t * 16;
    gl_lds16(WfB + (size_t)(nb * 128 + (d >> 7)) * 32768 + kbase + 1 * 128 + (d & 127),
             smem + 1 * 16384 + d);
  }
  __syncthreads();                       // slots 0,1 + x0t ready

  f32x4 acc[4][4] = {};
  _Float16 sh[4];
  const int browb = (wn * 64 + lr) * 128;

  // STEP: compute slot RD (=K%3); stage slot ST (=(K+2)%3) at top;
  // end with VM + one barrier. RD/ST/PAR literal; vmcnt never 0 in-loop.
#define STEP(K, RD, ST, PAR, DO_STAGE, VM) { \
    if (DO_STAGE) { \
      _Pragma("unroll") \
      for (int i = 0; i < 4; ++i) { \
        int d = i * 4096 + t * 16; \
        gl_lds16(WfB + (size_t)(nb * 128 + (d >> 7)) * 32768 + kbase + ((K) + 2) * 128 + (d & 127), \
                 smem + (ST) * 16384 + d); \
      } \
    } \
    if ((PAR) == 0) { \
      _Pragma("unroll") \
      for (int m = 0; m < 4; ++m) \
        sh[m] = (_Float16)x0t[((K) >> 1) * 128 + wm * 64 + m * 16 + lr]; \
    } \
    _Pragma("unroll") \
    for (int tp = 0; tp < 2; ++tp) { \
      f16x8 bw[4]; \
      _Pragma("unroll") \
      for (int n = 0; n < 4; ++n) \
        bw[n] = *(const f16x8*)(smem + (RD) * 16384 + browb + n * 2048 + \
                                (((tp * 4 + lg) ^ swz) << 4)); \
      _Pragma("unroll") \
      for (int m = 0; m < 4; ++m) { \
        f16x8 av = xr[m][PAR][tp] * sh[m]; \
        _Pragma("unroll") \
        for (int n = 0; n < 4; ++n) \
          acc[m][n] = __builtin_amdgcn_mfma_f32_16x16x32_f16( \
              av, bw[n], acc[m][n], 0, 0, 0); \
      } \
    } \
    VM; BAR(); \
  }

  for (int k3 = 0; k3 < 30; k3 += 6) {
    STEP(k3 + 0, 0, 2, 0, true, VMCNT4());
    STEP(k3 + 1, 1, 0, 1, true, VMCNT4());
    STEP(k3 + 2, 2, 1, 0, true, VMCNT4());
    STEP(k3 + 3, 0, 2, 1, true, VMCNT4());
    STEP(k3 + 4, 1, 0, 0, true, VMCNT4());
    STEP(k3 + 5, 2, 1, 1, true, VMCNT4());
  }
  STEP(30, 0, 0, 0, false, VMCNT0());
  STEP(31, 1, 0, 1, false, ;);
#undef STEP

  // ---- epilogue: split-K accumulate (out pre-initialized to bias) ----
  // C/D layout: col = lane&15, row = (lane>>4)*4 + reg
  float* op = out + (size_t)(mb * 128 + wm * 64 + lg * 4) * 256 +
              nb * 128 + wn * 64 + lr;
#pragma unroll
  for (int m = 0; m < 4; ++m)
#pragma unroll
    for (int n = 0; n < 4; ++n)
#pragma unroll
      for (int r = 0; r < 4; ++r)
        unsafeAtomicAdd(op + (size_t)(m * 16 + r) * 256 + n * 16,
                        acc[m][n][r]);
}

// --------------------------- fallback (no ws) ------------------------------
__global__ __launch_bounds__(256) void naive_kernel(
    const float* __restrict__ x0, const float* __restrict__ x,
    const float* __restrict__ W, const float* __restrict__ bias,
    float* __restrict__ out)
{
  __shared__ float x0_s[16][128];
  __shared__ float x_s[16][128];
  const int tid = threadIdx.x;
  const int b0  = blockIdx.x * 16;
  for (int i = tid; i < 16 * 128; i += 256) {
    int bb = i >> 7, c = i & 127;
    x0_s[bb][c] = x0[(size_t)(b0 + bb) * 128 + c];
    x_s[bb][c]  = x[(size_t)(b0 + bb) * 128 + c];
  }
  __syncthreads();
  const int lane = tid & 63, wv = tid >> 6;
  for (int o = wv; o < 256; o += 4) {
    float acc[16];
#pragma unroll
    for (int bb = 0; bb < 16; ++bb) acc[bb] = 0.f;
    for (int it = 0; it < 256; ++it) {
      int k = it * 64 + lane;
      float wval = W[(size_t)o * 16384 + k];
      int f = k >> 7, p = k & 127;
#pragma unroll
      for (int bb = 0; bb < 16; ++bb)
        acc[bb] += wval * (x0_s[bb][f] * x_s[bb][p]);
    }
#pragma unroll
    for (int bb = 0; bb < 16; ++bb) {
      float v = acc[bb];
      for (int off = 32; off; off >>= 1) v += __shfl_down(v, off);
      if (lane == 0) out[(size_t)(b0 + bb) * 256 + o] = v + bias[o];
    }
  }
}

// ------------------------------- launcher ----------------------------------
extern "C" void kernel_launch(void* const* d_in, const int* in_sizes, int n_in,
                              void* d_out, int out_size, void* d_ws,
                              size_t ws_size, hipStream_t stream)
{
  const float* x0   = (const float*)d_in[0];
  const float* x    = (const float*)d_in[1];
  const float* W    = (const float*)d_in[2];
  const float* bias = (const float*)d_in[3];
  float* out = (float*)d_out;

  if (ws_size >= (size_t)WS_NEEDED) {
    _Float16* Wf = (_Float16*)((char*)d_ws + WS_WF_OFF);
    _Float16* Xf = (_Float16*)((char*)d_ws + WS_XF_OFF);
    prep_kernel<<<3328, 256, 0, stream>>>(x, W, bias, Wf, Xf, out);
    gemm_kernel<<<512, 256, 0, stream>>>(Wf, Xf, x0, out);
  } else {
    naive_kernel<<<256, 256, 0, stream>>>(x0, x, W, bias, out);
  }
}